// Round 8
// baseline (436.356 us; speedup 1.0000x reference)
//
#include <hip/hip_runtime.h>

#define DIM 4096
#define BM 256
#define BN 256
#define BK 64
#define NT (DIM / BK)      // 64 K-tiles
#define THREADS 512        // 8 waves: 2 (M) x 4 (N)

typedef _Float16 half8 __attribute__((ext_vector_type(8)));
typedef _Float16 half4v __attribute__((ext_vector_type(4)));
typedef float floatx4 __attribute__((ext_vector_type(4)));

// Async global->LDS, 16B per lane. LDS dest is wave-uniform base + lane*16.
__device__ __forceinline__ void async_copy16(const _Float16* g, _Float16* l) {
    __builtin_amdgcn_global_load_lds(
        (const __attribute__((address_space(1))) void*)g,
        (__attribute__((address_space(3))) void*)l,
        16, 0, 0);
}

__device__ __forceinline__ void cfence() { asm volatile("" ::: "memory"); }
__device__ __forceinline__ void bar() { cfence(); __builtin_amdgcn_s_barrier(); cfence(); }
#define SB0() __builtin_amdgcn_sched_barrier(0)
#define MFMA16(a_, b_, c_) __builtin_amdgcn_mfma_f32_16x16x32_f16((a_), (b_), (c_), 0, 0, 0)

// 256x256 tile, BK=64 -- SOFTWARE-PIPELINED LDS reads (this round's change).
// Each window: issue next quadrant's 12 ds_reads into the OTHER frag bank,
// wait lgkmcnt(12) (= prior bank complete), stage, 16 MFMA on current bank,
// ONE barrier. Reads drain under the MFMA cluster instead of serializing
// before it; 4 barriers/K-tile instead of 8.
// vmcnt(0) sits BEFORE the W3/W7 barrier: every wave drains its own stages,
// then the barrier makes the next slot's data globally visible before any
// wave issues reads from it (airtight cross-wave ordering).
// LDS: [dbuf][A/B][half(128x64)] = 128 KiB. 3-bit XOR swizzle
// (16B-chunk ^ (row&7)) -> 0 bank conflicts (r2/r6/r7-verified).
// Compact 4x8 per-XCD block chunking (r6-verified: FETCH 147.9 -> 98.7 MB).
template <bool QUANT>
__global__ __launch_bounds__(THREADS, 2)
void gemm_bt(const _Float16* __restrict__ A,
             const _Float16* __restrict__ B,
             const float* __restrict__ cb,
             _Float16* __restrict__ Yq,
             float* __restrict__ C)
{
    __shared__ _Float16 lds[2][2][2][128 * BK];   // 128 KiB
    __shared__ float    s_bnd[15];
    __shared__ _Float16 s_cb[16];

    const int t    = threadIdx.x;
    const int lane = t & 63;
    const int wid  = t >> 6;            // 0..7
    const int wm   = (wid >> 2) * 128;  // wave M origin in tile
    const int wn   = (wid & 3) * 64;    // wave N origin in tile
    const int am   = wid >> 2;          // A half this wave reads
    const int bh   = (wid >> 1) & 1;    // B half this wave reads
    const int bro  = (wid & 1) * 64;    // row offset inside B half

    // Compact 4x8 per-XCD chunking (bijective; 256 blocks, 8 XCDs x 32).
    const int bid = blockIdx.y * gridDim.x + blockIdx.x;
    const int xcd = bid & 7;
    const int jj  = bid >> 3;                      // 0..31 within XCD
    const int prow = (xcd >> 1) * 4 + (jj >> 3);   // 0..15 M-panel
    const int pcol = (xcd & 1) * 8 + (jj & 7);     // 0..15 N-panel
    const int bm  = prow * BM;
    const int bn  = pcol * BN;

    if (QUANT) {
        if (t < 16) s_cb[t]  = (_Float16)cb[t];
        if (t < 15) s_bnd[t] = 0.5f * (cb[t] + cb[t + 1]);
    }

    // Staging: one 128x64 half-tile = 1024 16B chunks; thread t owns physical
    // chunks t and 512+t. Physical chunk p holds logical (row = p>>3,
    // col = (p&7) ^ ((p>>3)&7)) -> pre-swizzle the global source.
    const int pc0 = t, pc1 = 512 + t;
    const int goff0 = (pc0 >> 3) * DIM + ((pc0 & 7) ^ ((pc0 >> 3) & 7)) * 8;  // halves
    const int goff1 = (pc1 >> 3) * DIM + ((pc1 & 7) ^ ((pc1 >> 3) & 7)) * 8;

    auto stage = [&](const _Float16* srcrow0, _Float16* dst) {
        async_copy16(srcrow0 + goff0, dst + t * 8);
        async_copy16(srcrow0 + goff1, dst + (512 + t) * 8);
    };

    // MFMA 16x16x32 f16 fragment: elem[k = (lane>>4)*8 + j] of row (lane&15).
    // Swizzle inverse on read: physical col = (ks*4+kg) ^ (row&7); row&7 ==
    // frow&7 for all sub-tiles, so the XOR is a per-lane constant.
    const int frow  = lane & 15;
    const int kg    = lane >> 4;
    const int xr    = frow & 7;
    const int koff0 = ((0 + kg) ^ xr) * 8;   // ks = 0
    const int koff1 = ((4 + kg) ^ xr) * 8;   // ks = 1

    // LDS read base pointers, both slots (all offsets compile-time per window).
    const _Float16* A0p = &lds[0][0][am][0];
    const _Float16* B0p = &lds[0][1][bh][0];
    const _Float16* A1p = &lds[1][0][am][0];
    const _Float16* B1p = &lds[1][1][bh][0];

    // Two frag banks, ping-pong per window. 96 VGPRs total.
    half8 ra[2][2][4];   // [bank][ks][i]
    half8 rb[2][2][2];   // [bank][ks][j]
    floatx4 acc[8][4] = {};

// Issue 12 ds_reads for quadrant (IH,JH) from slot pointers into bank BK_.
#define READ_FRAGS(BK_, AP_, BP_, IH_, JH_)                                      \
    {                                                                            \
        _Pragma("unroll") for (int i = 0; i < 4; ++i) {                          \
            ra[BK_][0][i] = *(const half8*)((AP_) + ((IH_)*64 + i*16 + frow)*BK + koff0); \
            ra[BK_][1][i] = *(const half8*)((AP_) + ((IH_)*64 + i*16 + frow)*BK + koff1); \
        }                                                                        \
        _Pragma("unroll") for (int j = 0; j < 2; ++j) {                          \
            rb[BK_][0][j] = *(const half8*)((BP_) + (bro + ((JH_)*2 + j)*16 + frow)*BK + koff0); \
            rb[BK_][1][j] = *(const half8*)((BP_) + (bro + ((JH_)*2 + j)*16 + frow)*BK + koff1); \
        }                                                                        \
    }

// 16 MFMA for quadrant (IH,JH) consuming bank BK_.
#define MFMA_Q(BK_, IH_, JH_)                                                    \
    {                                                                            \
        __builtin_amdgcn_s_setprio(1);                                           \
        _Pragma("unroll") for (int i = 0; i < 4; ++i)                            \
            _Pragma("unroll") for (int j = 0; j < 2; ++j) {                      \
                acc[(IH_)*4+i][(JH_)*2+j] = MFMA16(ra[BK_][0][i], rb[BK_][0][j], acc[(IH_)*4+i][(JH_)*2+j]); \
                acc[(IH_)*4+i][(JH_)*2+j] = MFMA16(ra[BK_][1][i], rb[BK_][1][j], acc[(IH_)*4+i][(JH_)*2+j]); \
            }                                                                    \
        __builtin_amdgcn_s_setprio(0);                                           \
    }

#define LGKM12() do { asm volatile("s_waitcnt lgkmcnt(12)" ::: "memory"); SB0(); } while (0)

    // Prologue: K0 fully -> slot0 (8 loads), B(K1) -> slot1 (4 loads).
    // A(K1) is staged inside W1/W2 of the first iteration (uniform pattern).
    stage(B + (size_t)bn * DIM,               &lds[0][1][0][0]);
    stage(B + (size_t)(bn + 128) * DIM,       &lds[0][1][1][0]);
    stage(A + (size_t)bm * DIM,               &lds[0][0][0][0]);
    stage(A + (size_t)(bm + 128) * DIM,       &lds[0][0][1][0]);
    stage(B + (size_t)bn * DIM + BK,          &lds[1][1][0][0]);
    stage(B + (size_t)(bn + 128) * DIM + BK,  &lds[1][1][1][0]);
    asm volatile("s_waitcnt vmcnt(4) lgkmcnt(0)" ::: "memory");  // K0 landed; s_cb drained
    bar();
    READ_FRAGS(0, A0p, B0p, 0, 0);   // pre-issue Q1(T=0) -> bank0
    SB0();

#pragma unroll 1
    for (int T2 = 0; T2 < NT; T2 += 2) {
        const size_t k1 = (size_t)(T2 + 1) * BK;
        const size_t k2 = (size_t)(T2 + 2) * BK;
        const size_t k3 = (size_t)(T2 + 3) * BK;
        const bool st2 = (T2 + 2 < NT);
        const bool st3 = (T2 + 3 < NT);

        // ---- tile T2 (slot0) ----
        // W1: MFMA Q1(b0); issue Q2->b1; stage A0(T2+1)->slot1
        READ_FRAGS(1, A0p, B0p, 0, 1); SB0();
        LGKM12();
        stage(A + (size_t)bm * DIM + k1, &lds[1][0][0][0]);
        MFMA_Q(0, 0, 0);
        bar();

        // W2: MFMA Q2(b1); issue Q3->b0; stage A1(T2+1)->slot1
        READ_FRAGS(0, A0p, B0p, 1, 0); SB0();
        LGKM12();
        stage(A + (size_t)(bm + 128) * DIM + k1, &lds[1][0][1][0]);
        MFMA_Q(1, 0, 1);
        bar();

        // W3: MFMA Q3(b0); issue Q4->b1; vmcnt(0) pre-barrier (slot1 data all landed)
        READ_FRAGS(1, A0p, B0p, 1, 1); SB0();
        LGKM12();
        MFMA_Q(0, 1, 0);
        asm volatile("s_waitcnt vmcnt(0)" ::: "memory");
        bar();

        // W4: MFMA Q4(b1); issue Q1(T2+1, slot1)->b0; stage B(T2+2)->slot0
        READ_FRAGS(0, A1p, B1p, 0, 0); SB0();
        LGKM12();
        if (st2) {
            stage(B + (size_t)bn * DIM + k2,         &lds[0][1][0][0]);
            stage(B + (size_t)(bn + 128) * DIM + k2, &lds[0][1][1][0]);
        }
        MFMA_Q(1, 1, 1);
        bar();

        // ---- tile T2+1 (slot1) ----
        // W5: MFMA Q1(b0); issue Q2->b1; stage A0(T2+2)->slot0
        READ_FRAGS(1, A1p, B1p, 0, 1); SB0();
        LGKM12();
        if (st2) stage(A + (size_t)bm * DIM + k2, &lds[0][0][0][0]);
        MFMA_Q(0, 0, 0);
        bar();

        // W6: MFMA Q2(b1); issue Q3->b0; stage A1(T2+2)->slot0
        READ_FRAGS(0, A1p, B1p, 1, 0); SB0();
        LGKM12();
        if (st2) stage(A + (size_t)(bm + 128) * DIM + k2, &lds[0][0][1][0]);
        MFMA_Q(1, 0, 1);
        bar();

        // W7: MFMA Q3(b0); issue Q4->b1; vmcnt(0) pre-barrier (slot0 data all landed)
        READ_FRAGS(1, A1p, B1p, 1, 1); SB0();
        LGKM12();
        MFMA_Q(0, 1, 0);
        asm volatile("s_waitcnt vmcnt(0)" ::: "memory");
        bar();

        // W8: MFMA Q4(b1); issue Q1(T2+2, slot0)->b0; stage B(T2+3)->slot1
        if (st2) {
            READ_FRAGS(0, A0p, B0p, 0, 0); SB0();
            LGKM12();
        } else {
            asm volatile("s_waitcnt lgkmcnt(0)" ::: "memory"); SB0();
        }
        if (st3) {
            stage(B + (size_t)bn * DIM + k3,         &lds[1][1][0][0]);
            stage(B + (size_t)(bn + 128) * DIM + k3, &lds[1][1][1][0]);
        }
        MFMA_Q(1, 1, 1);
        bar();
    }
#undef READ_FRAGS
#undef MFMA_Q
#undef LGKM12

    // D layout: col = lane&15, row = (lane>>4)*4 + reg  [m89-verified]
    if (QUANT) {
        float bnd[15];
#pragma unroll
        for (int b = 0; b < 15; ++b) bnd[b] = s_bnd[b];
#pragma unroll
        for (int i = 0; i < 8; ++i) {
            const int gr0 = bm + wm + i * 16 + (lane >> 4) * 4;
#pragma unroll
            for (int j = 0; j < 4; ++j) {
                const int gc = bn + wn + j * 16 + frow;
#pragma unroll
                for (int rr = 0; rr < 4; ++rr) {
                    const float v = acc[i][j][rr];
                    int idx = 0;
#pragma unroll
                    for (int b = 0; b < 15; ++b) idx += (v > bnd[b]) ? 1 : 0;
                    Yq[(size_t)(gr0 + rr) * DIM + gc] = s_cb[idx];
                }
            }
        }
    } else {
#pragma unroll
        for (int i = 0; i < 8; ++i) {
            const int gr0 = bm + wm + i * 16 + (lane >> 4) * 4;
#pragma unroll
            for (int j = 0; j < 4; ++j) {
                const int gc = bn + wn + j * 16 + frow;
#pragma unroll
                for (int rr = 0; rr < 4; ++rr)
                    C[(size_t)(gr0 + rr) * DIM + gc] = acc[i][j][rr];
            }
        }
    }
}

// Fused prep: one launch does BOTH Pi->f16 (straight + transposed) and
// x->f16. Blocks [0, 4096): Pi 64x64 tiles; blocks [4096, 12288): x convert
// (8 f32->f16 per thread, 16B stores).
__global__ void prep_all(const float* __restrict__ Pi,
                         _Float16* __restrict__ Pif,
                         _Float16* __restrict__ PiT,
                         const float* __restrict__ x,
                         _Float16* __restrict__ xh)
{
    const int b = blockIdx.x;
    const int t = threadIdx.x;

    if (b >= 4096) {
        // ---- x -> f16, 8 elements/thread ----
        const size_t i = ((size_t)(b - 4096) * 256 + t) * 8;
        const float4 v0 = *(const float4*)(x + i);
        const float4 v1 = *(const float4*)(x + i + 4);
        half8 h;
        h[0] = (_Float16)v0.x; h[1] = (_Float16)v0.y;
        h[2] = (_Float16)v0.z; h[3] = (_Float16)v0.w;
        h[4] = (_Float16)v1.x; h[5] = (_Float16)v1.y;
        h[6] = (_Float16)v1.z; h[7] = (_Float16)v1.w;
        *(half8*)(xh + i) = h;
        return;
    }

    // ---- Pi tile: straight f16 + transposed f16 ----
    __shared__ _Float16 tile[64][68];
    const int r0 = t >> 4;          // 0..15
    const int c4 = (t & 15) * 4;    // 0..60
    const int y0 = (b >> 6) * 64;   // global row origin
    const int x0 = (b & 63) * 64;   // global col origin
#pragma unroll
    for (int ii = 0; ii < 4; ++ii) {
        const int r = ii * 16 + r0;
        const float4 v = *(const float4*)(Pi + (size_t)(y0 + r) * DIM + x0 + c4);
        half4v h;
        h.x = (_Float16)v.x; h.y = (_Float16)v.y; h.z = (_Float16)v.z; h.w = (_Float16)v.w;
        *(half4v*)(Pif + (size_t)(y0 + r) * DIM + x0 + c4) = h;
        tile[c4 + 0][r] = h.x;
        tile[c4 + 1][r] = h.y;
        tile[c4 + 2][r] = h.z;
        tile[c4 + 3][r] = h.w;
    }
    __syncthreads();
#pragma unroll
    for (int ii = 0; ii < 4; ++ii) {
        const int c = ii * 16 + r0;   // tile column = PiT row offset
        *(half4v*)(PiT + (size_t)(x0 + c) * DIM + y0 + c4) = *(const half4v*)&tile[c][c4];
    }
}

extern "C" void kernel_launch(void* const* d_in, const int* in_sizes, int n_in,
                              void* d_out, int out_size, void* d_ws, size_t ws_size,
                              hipStream_t stream)
{
    (void)in_sizes; (void)n_in; (void)out_size; (void)ws_size;
    const float* x  = (const float*)d_in[0];
    const float* Pi = (const float*)d_in[1];
    const float* cb = (const float*)d_in[2];
    float* out = (float*)d_out;

    char* ws = (char*)d_ws;
    const size_t MB32 = (size_t)DIM * DIM * sizeof(_Float16);  // 32 MiB
    _Float16* xh  = (_Float16*)(ws);
    _Float16* pih = (_Float16*)(ws + MB32);
    _Float16* pit = (_Float16*)(ws + 2 * MB32);
    _Float16* yh  = (_Float16*)(ws + 3 * MB32);

    // Fused prep: 4096 Pi-tile blocks + 8192 x-convert blocks.
    prep_all<<<dim3(4096 + 8192), dim3(256), 0, stream>>>(Pi, pih, pit, x, xh);

    // GEMM1: y = x @ Pi^T, fused Lloyd-Max quantize -> y_tilde (f16)
    gemm_bt<true><<<dim3(DIM / BM, DIM / BN), dim3(THREADS), 0, stream>>>(xh, pih, cb, yh, nullptr);
    // GEMM2: x_tilde = y_tilde @ Pi  ==  "bt" GEMM against PiT
    gemm_bt<false><<<dim3(DIM / BM, DIM / BN), dim3(THREADS), 0, stream>>>(yh, pit, cb, nullptr, out);
}